// Round 5
// baseline (811.627 us; speedup 1.0000x reference)
//
#include <hip/hip_runtime.h>

#define HIDDEN 1024
#define FFN    4096
#define NEXP   8
#define TOKENS 4096
#define ASSIGN 8192   // TOKENS * TOP_K
#define NENT   72     // max active (expert, tile_m) entries: 8192/128 + 7 = 71

typedef __attribute__((ext_vector_type(8))) short s8v;   // 8 x bf16 (A/B frag)
typedef __attribute__((ext_vector_type(4))) float f4v;   // 4 x f32  (C/D frag)

__device__ __forceinline__ float bf2f(ushort u) {
    return __uint_as_float(((unsigned int)u) << 16);
}
__device__ __forceinline__ ushort f2bf(float f) {
    unsigned int x = __float_as_uint(f);
    return (ushort)((x + 0x7fffu + ((x >> 16) & 1u)) >> 16);  // RNE
}

// fast erf-based exact gelu: Abramowitz-Stegun 7.1.26, |erf err| <= 1.5e-7
__device__ __forceinline__ float gelu_f(float v) {
    const float u = v * 0.70710678118654752f;
    const float a = fabsf(u);
    const float t = 1.0f / fmaf(0.3275911f, a, 1.0f);
    const float p = t * (0.254829592f + t * (-0.284496736f + t * (1.421413741f +
                     t * (-1.453152027f + t * 1.061405429f))));
    const float ex = __expf(-u * u);
    float er = 1.0f - p * ex;
    er = (u < 0.f) ? -er : er;
    return 0.5f * v * (1.0f + er);
}

#define GLDS16(g, l) __builtin_amdgcn_global_load_lds( \
    (const __attribute__((address_space(1))) unsigned int*)(g), \
    (__attribute__((address_space(3))) unsigned int*)(l), 16, 0, 0)

// ---- BK=32 LDS swizzle (verified 0-conflict rounds 1-4; m173/G21 pattern:
//      linear LDS dest, pre-swizzled global src, same XOR on read).
__device__ __forceinline__ int swz_scol(int t) {      // staging: global k-offset (elems)
    const int srow = t >> 2, c = t & 3;
    return ((c ^ ((srow >> 1) & 3)) << 3);
}
__device__ __forceinline__ int lds_off(int row, int lq) { // read: LDS elem offset
    return row * 32 + ((lq ^ ((row >> 1) & 3)) << 3);
}

// ---- T4 pipelined k-iteration body: 4-buffer, 3-ahead, counted vmcnt.
// At top of iter t (steady state): 12 loads outstanding (tiles t, t+1, t+2).
// vmcnt(8) -> tile t landed; t+1,t+2 stay in flight. Stage tile t+3 into the
// buffer last read at iter t-1 (reads completed before this barrier -> no WAR).
#define KBODY(it, bA, bB, sA, sB)                                               \
  {                                                                             \
    if ((it) == NT - 1)      { asm volatile("s_waitcnt vmcnt(0)" ::: "memory");}\
    else if ((it) == NT - 2) { asm volatile("s_waitcnt vmcnt(4)" ::: "memory");}\
    else                     { asm volatile("s_waitcnt vmcnt(8)" ::: "memory");}\
    __builtin_amdgcn_s_barrier();                                               \
    __builtin_amdgcn_sched_barrier(0);                                          \
    if ((it) + 3 < NT) {                                                        \
      const int kn_ = ((it) + 3) * 32;                                          \
      GLDS16(gA0 + kn_, (sA) + wv * 512);                                       \
      GLDS16(gA1 + kn_, (sA) + 2048 + wv * 512);                                \
      GLDS16(gB0 + kn_, (sB) + wv * 512);                                       \
      GLDS16(gB1 + kn_, (sB) + 2048 + wv * 512);                                \
    }                                                                           \
    s8v a_[4], b_[4];                                                           \
    _Pragma("unroll")                                                           \
    for (int i_ = 0; i_ < 4; ++i_)                                              \
      a_[i_] = *(const s8v*)((bA) + lds_off(row_off + i_ * 16 + l15, lq));      \
    _Pragma("unroll")                                                           \
    for (int j_ = 0; j_ < 4; ++j_)                                              \
      b_[j_] = *(const s8v*)((bB) + lds_off(col_off + j_ * 16 + l15, lq));      \
    __builtin_amdgcn_s_setprio(1);                                              \
    _Pragma("unroll")                                                           \
    for (int i_ = 0; i_ < 4; ++i_)                                              \
      _Pragma("unroll")                                                         \
      for (int j_ = 0; j_ < 4; ++j_)                                            \
        acc[i_][j_] = __builtin_amdgcn_mfma_f32_16x16x32_bf16(a_[i_], b_[j_],   \
                                                              acc[i_][j_], 0, 0, 0); \
    __builtin_amdgcn_s_setprio(0);                                              \
  }

// ---------------- fp32 -> bf16 streaming conversion ----------------
__global__ void conv_kernel(const float4* __restrict__ src, ushort4* __restrict__ dst) {
    const int i = blockIdx.x * blockDim.x + threadIdx.x;
    const float4 v = src[i];
    ushort4 o;
    o.x = f2bf(v.x); o.y = f2bf(v.y); o.z = f2bf(v.z); o.w = f2bf(v.w);
    dst[i] = o;
}

// ---------------- router: fp32 logits -> softmax -> top2 -> counts ----------------
__global__ void router_kernel(const float* __restrict__ x, const float* __restrict__ Wr,
                              int* __restrict__ counts, int* __restrict__ topk_idx,
                              float* __restrict__ topk_w) {
    const int tok  = blockIdx.x;
    const int lane = threadIdx.x;   // block = 64 (one wave)
    float acc[NEXP];
#pragma unroll
    for (int e = 0; e < NEXP; ++e) acc[e] = 0.f;
#pragma unroll
    for (int i = 0; i < HIDDEN / 64; ++i) {
        const int idx = i * 64 + lane;
        const float xv = x[(size_t)tok * HIDDEN + idx];
#pragma unroll
        for (int e = 0; e < NEXP; ++e) acc[e] += xv * Wr[e * HIDDEN + idx];
    }
#pragma unroll
    for (int e = 0; e < NEXP; ++e) {
#pragma unroll
        for (int off = 32; off > 0; off >>= 1) acc[e] += __shfl_xor(acc[e], off);
    }
    if (lane == 0) {
        int i0 = 0;
        for (int e = 1; e < NEXP; ++e) if (acc[e] > acc[i0]) i0 = e;  // ties -> lowest idx
        int i1 = (i0 == 0) ? 1 : 0;
        for (int e = 0; e < NEXP; ++e) if (e != i0 && acc[e] > acc[i1]) i1 = e;
        const float e1 = expf(acc[i1] - acc[i0]);   // <= 1
        const float s  = 1.f + e1;
        topk_idx[tok * 2 + 0] = i0;
        topk_idx[tok * 2 + 1] = i1;
        topk_w[tok * 2 + 0]   = 1.f / s;
        topk_w[tok * 2 + 1]   = e1 / s;
        atomicAdd(&counts[i0], 1);
        atomicAdd(&counts[i1], 1);
    }
}

// ---------------- prefix + compact tile table ----------------
__global__ void prefix_kernel(const int* __restrict__ counts, int* __restrict__ offsets,
                              int* __restrict__ cursors, int* __restrict__ tiles) {
    if (threadIdx.x == 0) {
        int s = 0, nt = 0;
        for (int e = 0; e < NEXP; ++e) {
            offsets[e] = s; cursors[e] = s;
            const int ne = counts[e];
            for (int tm = 0; tm * 128 < ne; ++tm) tiles[nt++] = e | (tm << 8);
            s += ne;
        }
        offsets[NEXP] = s;   // == ASSIGN
        for (; nt < NENT; ++nt) tiles[nt] = -1;
    }
}

// ---------------- compact assignments into per-expert slot lists ----------------
__global__ void scatter_kernel(const int* __restrict__ topk_idx, const float* __restrict__ topk_w,
                               int* __restrict__ cursors, int* __restrict__ token_list,
                               float* __restrict__ weight_list) {
    const int a = blockIdx.x * blockDim.x + threadIdx.x;
    if (a >= ASSIGN) return;
    const int e   = topk_idx[a];
    const int pos = atomicAdd(&cursors[e], 1);
    token_list[pos]  = a >> 1;        // token id
    weight_list[pos] = topk_w[a];
}

// ---------------- GEMM1: h[slot, F] = gelu(x[tok] @ W1[e]^T + b1[e]) ----------------
// 128x128 tile, BK=32, 4-buffer 3-ahead counted-vmcnt pipeline.
// Grid (entry, tile_n); consecutive dispatches share the B panel (tile_m fastest).
__global__ __launch_bounds__(256)
void gemm1_kernel(const ushort* __restrict__ x, const ushort* __restrict__ W1,
                  const float* __restrict__ b1, const int* __restrict__ token_list,
                  const int* __restrict__ counts, const int* __restrict__ offsets,
                  const int* __restrict__ tiles, ushort* __restrict__ h) {
    const int info = tiles[blockIdx.x];
    if (info < 0) return;
    const int e      = info & 255;
    const int tile_m = info >> 8;
    const int tile_n = blockIdx.y;    // 0..31
    const int n_e    = counts[e];
    const int base   = offsets[e];

    __shared__ __align__(16) ushort As[4 * 128 * 32];   // 4 x 8 KB
    __shared__ __align__(16) ushort Bs[4 * 128 * 32];   // 4 x 8 KB

    const int t    = threadIdx.x;
    const int lane = t & 63;
    const int wv   = t >> 6;
    const int srow = t >> 2;          // 0..63 staging row
    const int scol = swz_scol(t);     // pre-swizzled k-offset (elements)

    const int r0 = tile_m * 128 + srow;
    const int r1 = r0 + 64;
    const int tokA0 = token_list[base + (r0 < n_e ? r0 : n_e - 1)];
    const int tokA1 = token_list[base + (r1 < n_e ? r1 : n_e - 1)];
    const ushort* gA0 = x + (size_t)tokA0 * HIDDEN + scol;
    const ushort* gA1 = x + (size_t)tokA1 * HIDDEN + scol;
    const ushort* gB0 = W1 + ((size_t)e * FFN + tile_n * 128 + srow) * HIDDEN + scol;
    const ushort* gB1 = W1 + ((size_t)e * FFN + tile_n * 128 + 64 + srow) * HIDDEN + scol;

    f4v acc[4][4];
#pragma unroll
    for (int i = 0; i < 4; ++i)
#pragma unroll
        for (int j = 0; j < 4; ++j) { f4v z = {0.f, 0.f, 0.f, 0.f}; acc[i][j] = z; }

    const int row_off = (wv & 1) * 64;
    const int col_off = (wv >> 1) * 64;
    const int l15 = lane & 15;
    const int lq  = lane >> 4;

    const int NT = HIDDEN / 32;   // 32 (divisible by 4)

    // prologue: stage tiles 0,1,2 -> bufs 0,1,2  (12 loads in flight)
#pragma unroll
    for (int p = 0; p < 3; ++p) {
        GLDS16(gA0 + p * 32, As + p * 4096 + wv * 512);
        GLDS16(gA1 + p * 32, As + p * 4096 + 2048 + wv * 512);
        GLDS16(gB0 + p * 32, Bs + p * 4096 + wv * 512);
        GLDS16(gB1 + p * 32, Bs + p * 4096 + 2048 + wv * 512);
    }

    // unroll-by-4: static buffer bases (rule #20); stage buf = (it+3)&3
    for (int it0 = 0; it0 < NT; it0 += 4) {
        KBODY(it0 + 0, As + 0 * 4096, Bs + 0 * 4096, As + 3 * 4096, Bs + 3 * 4096);
        KBODY(it0 + 1, As + 1 * 4096, Bs + 1 * 4096, As + 0 * 4096, Bs + 0 * 4096);
        KBODY(it0 + 2, As + 2 * 4096, Bs + 2 * 4096, As + 1 * 4096, Bs + 1 * 4096);
        KBODY(it0 + 3, As + 3 * 4096, Bs + 3 * 4096, As + 2 * 4096, Bs + 2 * 4096);
    }

    const int mrem = n_e - tile_m * 128;
#pragma unroll
    for (int i = 0; i < 4; ++i) {
#pragma unroll
        for (int rr = 0; rr < 4; ++rr) {
            const int m_loc = row_off + i * 16 + lq * 4 + rr;
            if (m_loc < mrem) {
                const size_t hrow = (size_t)(base + tile_m * 128 + m_loc) * FFN;
#pragma unroll
                for (int j = 0; j < 4; ++j) {
                    const int colF = tile_n * 128 + col_off + j * 16 + l15;
                    const float v = gelu_f(acc[i][j][rr] + b1[e * FFN + colF]);
                    h[hrow + colF] = f2bf(v);
                }
            }
        }
    }
}

// ---------------- GEMM2: out[tok] += (h[slot] @ W2[e]^T + b2[e]) * gate ----------------
// Same pipeline, K = FFN (NT = 128). Combine fused via fp32 atomicAdd on out
// (out pre-zeroed; 2 commutative adds per element -> deterministic).
__global__ __launch_bounds__(256)
void gemm2_kernel(const ushort* __restrict__ h, const ushort* __restrict__ W2,
                  const float* __restrict__ b2, const float* __restrict__ weight_list,
                  const int* __restrict__ token_list, const int* __restrict__ counts,
                  const int* __restrict__ offsets, const int* __restrict__ tiles,
                  float* __restrict__ out) {
    const int info = tiles[blockIdx.x];
    if (info < 0) return;
    const int e      = info & 255;
    const int tile_m = info >> 8;
    const int tile_n = blockIdx.y;    // 0..7
    const int n_e    = counts[e];
    const int base   = offsets[e];

    __shared__ __align__(16) ushort As[4 * 128 * 32];
    __shared__ __align__(16) ushort Bs[4 * 128 * 32];

    const int t    = threadIdx.x;
    const int lane = t & 63;
    const int wv   = t >> 6;
    const int srow = t >> 2;
    const int scol = swz_scol(t);

    const int r0 = tile_m * 128 + srow;
    const int r1 = r0 + 64;
    const int slot0 = base + (r0 < n_e ? r0 : n_e - 1);
    const int slot1 = base + (r1 < n_e ? r1 : n_e - 1);
    const ushort* gA0 = h + (size_t)slot0 * FFN + scol;
    const ushort* gA1 = h + (size_t)slot1 * FFN + scol;
    const ushort* gB0 = W2 + ((size_t)e * HIDDEN + tile_n * 128 + srow) * FFN + scol;
    const ushort* gB1 = W2 + ((size_t)e * HIDDEN + tile_n * 128 + 64 + srow) * FFN + scol;

    f4v acc[4][4];
#pragma unroll
    for (int i = 0; i < 4; ++i)
#pragma unroll
        for (int j = 0; j < 4; ++j) { f4v z = {0.f, 0.f, 0.f, 0.f}; acc[i][j] = z; }

    const int row_off = (wv & 1) * 64;
    const int col_off = (wv >> 1) * 64;
    const int l15 = lane & 15;
    const int lq  = lane >> 4;

    const int NT = FFN / 32;   // 128 (divisible by 4)

    // prologue: stage tiles 0,1,2 -> bufs 0,1,2
#pragma unroll
    for (int p = 0; p < 3; ++p) {
        GLDS16(gA0 + p * 32, As + p * 4096 + wv * 512);
        GLDS16(gA1 + p * 32, As + p * 4096 + 2048 + wv * 512);
        GLDS16(gB0 + p * 32, Bs + p * 4096 + wv * 512);
        GLDS16(gB1 + p * 32, Bs + p * 4096 + 2048 + wv * 512);
    }

    for (int it0 = 0; it0 < NT; it0 += 4) {
        KBODY(it0 + 0, As + 0 * 4096, Bs + 0 * 4096, As + 3 * 4096, Bs + 3 * 4096);
        KBODY(it0 + 1, As + 1 * 4096, Bs + 1 * 4096, As + 0 * 4096, Bs + 0 * 4096);
        KBODY(it0 + 2, As + 2 * 4096, Bs + 2 * 4096, As + 1 * 4096, Bs + 1 * 4096);
        KBODY(it0 + 3, As + 3 * 4096, Bs + 3 * 4096, As + 2 * 4096, Bs + 2 * 4096);
    }

    const int mrem = n_e - tile_m * 128;
#pragma unroll
    for (int i = 0; i < 4; ++i) {
#pragma unroll
        for (int rr = 0; rr < 4; ++rr) {
            const int m_loc = row_off + i * 16 + lq * 4 + rr;
            if (m_loc < mrem) {
                const int slot  = base + tile_m * 128 + m_loc;
                const float wgt = weight_list[slot];
                const int   tok = token_list[slot];
#pragma unroll
                for (int j = 0; j < 4; ++j) {
                    const int colD = tile_n * 128 + col_off + j * 16 + l15;
                    const float v = acc[i][j][rr] + b2[e * HIDDEN + colD];
                    atomicAdd(&out[(size_t)tok * HIDDEN + colD], v * wgt);
                }
            }
        }
    }
}

extern "C" void kernel_launch(void* const* d_in, const int* in_sizes, int n_in,
                              void* d_out, int out_size, void* d_ws, size_t ws_size,
                              hipStream_t stream) {
    const float* x  = (const float*)d_in[0];   // [T, D] fp32
    const float* Wr = (const float*)d_in[1];   // [E, D]
    const float* W1 = (const float*)d_in[2];   // [E, F, D]
    const float* b1 = (const float*)d_in[3];   // [E, F]
    const float* W2 = (const float*)d_in[4];   // [E, D, F]
    const float* b2 = (const float*)d_in[5];   // [E, D]
    float* out = (float*)d_out;

    char* ws = (char*)d_ws;
    int*    counts      = (int*)(ws + 0);
    int*    offsets     = (int*)(ws + 256);
    int*    cursors     = (int*)(ws + 512);
    int*    tiles       = (int*)(ws + 768);            // NENT ints
    int*    topk_idx    = (int*)(ws + 2048);           // 32 KB
    float*  topk_w      = (float*)(ws + 2048 + 32768); // 16 KB
    int*    token_list  = (int*)(ws + 2048 + 65536);   // 32 KB
    float*  weight_list = (float*)(ws + 2048 + 98304); // 32 KB
    ushort* x_bf        = (ushort*)(ws + (1 << 20));                             //  8 MB
    ushort* wbuf        = (ushort*)(ws + (1 << 20) + 8388608);                   // 64 MB (shared W1/W2)
    ushort* h           = (ushort*)(ws + (1 << 20) + 8388608 + 67108864);        // 64 MB

    const int NW = NEXP * FFN * HIDDEN;  // 33554432 elements per weight tensor

    hipMemsetAsync(counts, 0, 64, stream);
    hipMemsetAsync(out, 0, (size_t)TOKENS * HIDDEN * 4, stream);   // fused-combine target
    // x -> bf16
    conv_kernel<<<(TOKENS * HIDDEN / 4) / 256, 256, 0, stream>>>((const float4*)x, (ushort4*)x_bf);
    // W1 -> bf16 (into shared wbuf)
    conv_kernel<<<(NW / 4) / 256, 256, 0, stream>>>((const float4*)W1, (ushort4*)wbuf);

    router_kernel<<<TOKENS, 64, 0, stream>>>(x, Wr, counts, topk_idx, topk_w);
    prefix_kernel<<<1, 64, 0, stream>>>(counts, offsets, cursors, tiles);
    scatter_kernel<<<ASSIGN / 256, 256, 0, stream>>>(topk_idx, topk_w, cursors,
                                                     token_list, weight_list);

    gemm1_kernel<<<dim3(NENT, FFN / 128), 256, 0, stream>>>(
        x_bf, wbuf, b1, token_list, counts, offsets, tiles, h);

    // W2 -> bf16 (reuse wbuf; stream-serial so gemm1 has finished reading W1)
    conv_kernel<<<(NW / 4) / 256, 256, 0, stream>>>((const float4*)W2, (ushort4*)wbuf);

    gemm2_kernel<<<dim3(NENT, HIDDEN / 128), 256, 0, stream>>>(
        h, wbuf, b2, weight_list, token_list, counts, offsets, tiles, out);
}

// Round 6
// 706.463 us; speedup vs baseline: 1.1489x; 1.1489x over previous
//
#include <hip/hip_runtime.h>

#define HIDDEN 1024
#define FFN    4096
#define NEXP   8
#define TOKENS 4096
#define ASSIGN 8192   // TOKENS * TOP_K
#define NENT   40     // max (expert, tile_m256) entries: 8192/256 + 7 = 39

typedef __attribute__((ext_vector_type(8))) short s8v;   // 8 x bf16 (A/B frag)
typedef __attribute__((ext_vector_type(4))) float f4v;   // 4 x f32  (C/D frag)

__device__ __forceinline__ float bf2f(ushort u) {
    return __uint_as_float(((unsigned int)u) << 16);
}
__device__ __forceinline__ ushort f2bf(float f) {
    unsigned int x = __float_as_uint(f);
    return (ushort)((x + 0x7fffu + ((x >> 16) & 1u)) >> 16);  // RNE
}

// fast erf-based exact gelu (A&S 7.1.26, |err| <= 1.5e-7) — verified pass in r5
__device__ __forceinline__ float gelu_f(float v) {
    const float u = v * 0.70710678118654752f;
    const float a = fabsf(u);
    const float t = 1.0f / fmaf(0.3275911f, a, 1.0f);
    const float p = t * (0.254829592f + t * (-0.284496736f + t * (1.421413741f +
                     t * (-1.453152027f + t * 1.061405429f))));
    const float ex = __expf(-u * u);
    float er = 1.0f - p * ex;
    er = (u < 0.f) ? -er : er;
    return 0.5f * v * (1.0f + er);
}

#define GLDS16(g, l) __builtin_amdgcn_global_load_lds( \
    (const __attribute__((address_space(1))) unsigned int*)(g), \
    (__attribute__((address_space(3))) unsigned int*)(l), 16, 0, 0)

// ---- BK=32 LDS swizzle (verified 0-conflict in rounds 1/3/4; m173/G21 pattern:
//      linear LDS dest, pre-swizzled global src, same XOR on read).
__device__ __forceinline__ int swz_scol(int t) {      // staging: global k-offset (elems)
    return (((t & 3) ^ ((t >> 3) & 3)) << 3);
}
__device__ __forceinline__ int lds_off(int row, int lq) { // read: LDS elem offset
    return row * 32 + ((lq ^ ((row >> 1) & 3)) << 3);
}

// ---------------- fp32 -> bf16 streaming conversion (weights) ----------------
__global__ void conv_kernel(const float4* __restrict__ src, ushort4* __restrict__ dst) {
    const int i = blockIdx.x * blockDim.x + threadIdx.x;
    const float4 v = src[i];
    ushort4 o;
    o.x = f2bf(v.x); o.y = f2bf(v.y); o.z = f2bf(v.z); o.w = f2bf(v.w);
    dst[i] = o;
}

// ---------------- router (+ fused x -> bf16) ----------------
__global__ void router_kernel(const float* __restrict__ x, const float* __restrict__ Wr,
                              int* __restrict__ counts, int* __restrict__ topk_idx,
                              float* __restrict__ topk_w, ushort* __restrict__ x_bf) {
    const int tok  = blockIdx.x;
    const int lane = threadIdx.x;   // block = 64 (one wave)
    float acc[NEXP];
#pragma unroll
    for (int e = 0; e < NEXP; ++e) acc[e] = 0.f;
#pragma unroll
    for (int i = 0; i < HIDDEN / 64; ++i) {
        const int idx = i * 64 + lane;
        const float xv = x[(size_t)tok * HIDDEN + idx];
        x_bf[(size_t)tok * HIDDEN + idx] = f2bf(xv);
#pragma unroll
        for (int e = 0; e < NEXP; ++e) acc[e] += xv * Wr[e * HIDDEN + idx];
    }
#pragma unroll
    for (int e = 0; e < NEXP; ++e) {
#pragma unroll
        for (int off = 32; off > 0; off >>= 1) acc[e] += __shfl_xor(acc[e], off);
    }
    if (lane == 0) {
        int i0 = 0;
        for (int e = 1; e < NEXP; ++e) if (acc[e] > acc[i0]) i0 = e;  // ties -> lowest idx
        int i1 = (i0 == 0) ? 1 : 0;
        for (int e = 0; e < NEXP; ++e) if (e != i0 && acc[e] > acc[i1]) i1 = e;
        const float e1 = expf(acc[i1] - acc[i0]);   // <= 1
        const float s  = 1.f + e1;
        topk_idx[tok * 2 + 0] = i0;
        topk_idx[tok * 2 + 1] = i1;
        topk_w[tok * 2 + 0]   = 1.f / s;
        topk_w[tok * 2 + 1]   = e1 / s;
        atomicAdd(&counts[i0], 1);
        atomicAdd(&counts[i1], 1);
    }
}

// ---------------- prefix + compact 256-row tile table ----------------
__global__ void prefix_kernel(const int* __restrict__ counts, int* __restrict__ offsets,
                              int* __restrict__ cursors, int* __restrict__ tiles) {
    if (threadIdx.x == 0) {
        int s = 0, nt = 0;
        for (int e = 0; e < NEXP; ++e) {
            offsets[e] = s; cursors[e] = s;
            const int ne = counts[e];
            for (int tm = 0; tm * 256 < ne; ++tm) tiles[nt++] = e | (tm << 8);
            s += ne;
        }
        offsets[NEXP] = s;   // == ASSIGN
        for (; nt < NENT; ++nt) tiles[nt] = -1;
    }
}

// ---------------- compact assignments into per-expert slot lists ----------------
__global__ void scatter_kernel(const int* __restrict__ topk_idx, const float* __restrict__ topk_w,
                               int* __restrict__ cursors, int* __restrict__ token_list,
                               float* __restrict__ weight_list, int* __restrict__ slot_of) {
    const int a = blockIdx.x * blockDim.x + threadIdx.x;
    if (a >= ASSIGN) return;
    const int e   = topk_idx[a];
    const int pos = atomicAdd(&cursors[e], 1);
    token_list[pos]  = a >> 1;        // token id
    weight_list[pos] = topk_w[a];
    slot_of[a]       = pos;
}

// ================= GEMM1: 256x256 tile, 8 waves, BK=32, 3-buf 2-ahead =================
// One barrier per K-tile; uniform vmcnt(4): at end of tile t, outstanding =
// t+1's 4 calls + t+2's 4 calls; vmcnt(4) drains t+1 (needed next), keeps t+2
// in flight. WAR: stage target buf (t+2)%3 was last read at tile t-1, retired
// before the intervening barrier. RAW: each wave's own vmcnt covers its staged
// slice; barrier makes it collective.
#define G1_TILE(T, CA, CB, SA, SB)                                              \
  if ((T) < NT) {                                                               \
    if ((T) + 2 < NT) {                                                         \
      const int kn_ = ((T) + 2) * 32;                                           \
      GLDS16(gA0 + kn_, (SA) + wv * 512);                                       \
      GLDS16(gA1 + kn_, (SA) + 4096 + wv * 512);                                \
      GLDS16(gB0 + kn_, (SB) + wv * 512);                                       \
      GLDS16(gB1 + kn_, (SB) + 4096 + wv * 512);                                \
    }                                                                           \
    s8v a_[4], b_[4], c_[4];                                                    \
    _Pragma("unroll")                                                           \
    for (int i_ = 0; i_ < 4; ++i_)                                              \
      a_[i_] = *(const s8v*)((CA) + lds_off(wm * 128 + i_ * 16 + l15, lq));     \
    _Pragma("unroll")                                                           \
    for (int j_ = 0; j_ < 4; ++j_)                                              \
      b_[j_] = *(const s8v*)((CB) + lds_off(wn * 64 + j_ * 16 + l15, lq));      \
    _Pragma("unroll")                                                           \
    for (int i_ = 0; i_ < 4; ++i_)                                              \
      c_[i_] = *(const s8v*)((CA) + lds_off(wm * 128 + 64 + i_ * 16 + l15, lq));\
    __builtin_amdgcn_s_setprio(1);                                              \
    _Pragma("unroll")                                                           \
    for (int i_ = 0; i_ < 4; ++i_)                                              \
      _Pragma("unroll")                                                         \
      for (int j_ = 0; j_ < 4; ++j_)                                            \
        acc[i_][j_] = __builtin_amdgcn_mfma_f32_16x16x32_bf16(a_[i_], b_[j_],   \
                                                              acc[i_][j_], 0, 0, 0); \
    _Pragma("unroll")                                                           \
    for (int i_ = 0; i_ < 4; ++i_)                                              \
      _Pragma("unroll")                                                         \
      for (int j_ = 0; j_ < 4; ++j_)                                            \
        acc[4 + i_][j_] = __builtin_amdgcn_mfma_f32_16x16x32_bf16(c_[i_], b_[j_], \
                                                              acc[4 + i_][j_], 0, 0, 0); \
    __builtin_amdgcn_s_setprio(0);                                              \
    if ((T) >= NT - 2) { asm volatile("s_waitcnt vmcnt(0)" ::: "memory"); }     \
    else               { asm volatile("s_waitcnt vmcnt(4)" ::: "memory"); }     \
    __builtin_amdgcn_s_barrier();                                               \
    __builtin_amdgcn_sched_barrier(0);                                          \
  }

__global__ __launch_bounds__(512, 2)
void gemm1_kernel(const ushort* __restrict__ x, const ushort* __restrict__ W1,
                  const float* __restrict__ b1, const int* __restrict__ token_list,
                  const int* __restrict__ counts, const int* __restrict__ offsets,
                  const int* __restrict__ tiles, ushort* __restrict__ h) {
    const int info = tiles[blockIdx.y];
    if (info < 0) return;
    const int e      = info & 255;
    const int tile_m = info >> 8;
    const int tile_n = blockIdx.x;    // 0..15 (fastest -> B-panel peers 8 apart = same XCD)
    const int n_e    = counts[e];
    const int base   = offsets[e];

    __shared__ __align__(16) ushort As[3 * 256 * 32];   // 3 x 16 KB
    __shared__ __align__(16) ushort Bs[3 * 256 * 32];   // 3 x 16 KB

    const int t    = threadIdx.x;     // 0..511
    const int wv   = t >> 6;          // 0..7
    const int lane = t & 63;
    const int srow = t >> 2;          // 0..127 staging row
    const int scol = swz_scol(t);     // pre-swizzled k-offset (elements)

    const int r0 = tile_m * 256 + srow;
    const int r1 = r0 + 128;
    const int tokA0 = token_list[base + (r0 < n_e ? r0 : n_e - 1)];
    const int tokA1 = token_list[base + (r1 < n_e ? r1 : n_e - 1)];
    const ushort* gA0 = x + (size_t)tokA0 * HIDDEN + scol;
    const ushort* gA1 = x + (size_t)tokA1 * HIDDEN + scol;
    const ushort* gB0 = W1 + ((size_t)e * FFN + tile_n * 256 + srow) * HIDDEN + scol;
    const ushort* gB1 = W1 + ((size_t)e * FFN + tile_n * 256 + 128 + srow) * HIDDEN + scol;

    f4v acc[8][4];
#pragma unroll
    for (int i = 0; i < 8; ++i)
#pragma unroll
        for (int j = 0; j < 4; ++j) { f4v z = {0.f, 0.f, 0.f, 0.f}; acc[i][j] = z; }

    const int wm  = wv >> 2;          // 0..1  (M half: 128 rows)
    const int wn  = wv & 3;           // 0..3  (N quarter: 64 cols)
    const int l15 = lane & 15;
    const int lq  = lane >> 4;

    const int NT = HIDDEN / 32;       // 32

    // prologue: stage tiles 0,1 -> bufs 0,1 (8 calls in flight)
#pragma unroll
    for (int p = 0; p < 2; ++p) {
        GLDS16(gA0 + p * 32, As + p * 8192 + wv * 512);
        GLDS16(gA1 + p * 32, As + p * 8192 + 4096 + wv * 512);
        GLDS16(gB0 + p * 32, Bs + p * 8192 + wv * 512);
        GLDS16(gB1 + p * 32, Bs + p * 8192 + 4096 + wv * 512);
    }
    asm volatile("s_waitcnt vmcnt(4)" ::: "memory");   // tile 0 landed; tile 1 in flight
    __builtin_amdgcn_s_barrier();
    __builtin_amdgcn_sched_barrier(0);

    for (int t0 = 0; t0 < NT; t0 += 3) {
        G1_TILE(t0 + 0, As + 0 * 8192, Bs + 0 * 8192, As + 2 * 8192, Bs + 2 * 8192);
        G1_TILE(t0 + 1, As + 1 * 8192, Bs + 1 * 8192, As + 0 * 8192, Bs + 0 * 8192);
        G1_TILE(t0 + 2, As + 2 * 8192, Bs + 2 * 8192, As + 1 * 8192, Bs + 1 * 8192);
    }

    const int mrem = n_e - tile_m * 256;
#pragma unroll
    for (int i = 0; i < 8; ++i) {
#pragma unroll
        for (int rr = 0; rr < 4; ++rr) {
            const int m_loc = wm * 128 + i * 16 + lq * 4 + rr;
            if (m_loc < mrem) {
                const size_t hrow = (size_t)(base + tile_m * 256 + m_loc) * FFN;
#pragma unroll
                for (int j = 0; j < 4; ++j) {
                    const int colF = tile_n * 256 + wn * 64 + j * 16 + l15;
                    const float v = gelu_f(acc[i][j][rr] + b1[e * FFN + colF]);
                    h[hrow + colF] = f2bf(v);
                }
            }
        }
    }
}

// ================= GEMM2: 256x128 tile, 8 waves, BK=32, 3-buf 2-ahead =================
#define G2_TILE(T, CA, CB, SA, SB)                                              \
  if ((T) < NT) {                                                               \
    if ((T) + 2 < NT) {                                                         \
      const int kn_ = ((T) + 2) * 32;                                           \
      GLDS16(gA0 + kn_, (SA) + wv * 512);                                       \
      GLDS16(gA1 + kn_, (SA) + 4096 + wv * 512);                                \
      GLDS16(gB0 + kn_, (SB) + wv * 512);                                       \
    }                                                                           \
    s8v a_[4], b_[2], c_[4];                                                    \
    _Pragma("unroll")                                                           \
    for (int i_ = 0; i_ < 4; ++i_)                                              \
      a_[i_] = *(const s8v*)((CA) + lds_off(wm * 128 + i_ * 16 + l15, lq));     \
    _Pragma("unroll")                                                           \
    for (int j_ = 0; j_ < 2; ++j_)                                              \
      b_[j_] = *(const s8v*)((CB) + lds_off(wn * 32 + j_ * 16 + l15, lq));      \
    _Pragma("unroll")                                                           \
    for (int i_ = 0; i_ < 4; ++i_)                                              \
      c_[i_] = *(const s8v*)((CA) + lds_off(wm * 128 + 64 + i_ * 16 + l15, lq));\
    __builtin_amdgcn_s_setprio(1);                                              \
    _Pragma("unroll")                                                           \
    for (int i_ = 0; i_ < 4; ++i_)                                              \
      _Pragma("unroll")                                                         \
      for (int j_ = 0; j_ < 2; ++j_)                                            \
        acc[i_][j_] = __builtin_amdgcn_mfma_f32_16x16x32_bf16(a_[i_], b_[j_],   \
                                                              acc[i_][j_], 0, 0, 0); \
    _Pragma("unroll")                                                           \
    for (int i_ = 0; i_ < 4; ++i_)                                              \
      _Pragma("unroll")                                                         \
      for (int j_ = 0; j_ < 2; ++j_)                                            \
        acc[4 + i_][j_] = __builtin_amdgcn_mfma_f32_16x16x32_bf16(c_[i_], b_[j_], \
                                                              acc[4 + i_][j_], 0, 0, 0); \
    __builtin_amdgcn_s_setprio(0);                                              \
    if ((T) >= NT - 2) { asm volatile("s_waitcnt vmcnt(0)" ::: "memory"); }     \
    else               { asm volatile("s_waitcnt vmcnt(3)" ::: "memory"); }     \
    __builtin_amdgcn_s_barrier();                                               \
    __builtin_amdgcn_sched_barrier(0);                                          \
  }

__global__ __launch_bounds__(512, 2)
void gemm2_kernel(const ushort* __restrict__ h, const ushort* __restrict__ W2,
                  const float* __restrict__ b2, const float* __restrict__ weight_list,
                  const int* __restrict__ counts, const int* __restrict__ offsets,
                  const int* __restrict__ tiles, ushort* __restrict__ y) {
    const int info = tiles[blockIdx.y];
    if (info < 0) return;
    const int e      = info & 255;
    const int tile_m = info >> 8;
    const int tile_n = blockIdx.x;    // 0..7 (fastest -> per-tile_n W2 slice pinned per XCD)
    const int n_e    = counts[e];
    const int base   = offsets[e];

    __shared__ __align__(16) ushort As[3 * 256 * 32];   // 3 x 16 KB
    __shared__ __align__(16) ushort Bs[3 * 128 * 32];   // 3 x 8 KB

    const int t    = threadIdx.x;
    const int wv   = t >> 6;
    const int lane = t & 63;
    const int srow = t >> 2;          // 0..127
    const int scol = swz_scol(t);

    const int r0 = tile_m * 256 + srow;
    const int r1 = r0 + 128;
    const int slot0 = base + (r0 < n_e ? r0 : n_e - 1);
    const int slot1 = base + (r1 < n_e ? r1 : n_e - 1);
    const ushort* gA0 = h + (size_t)slot0 * FFN + scol;
    const ushort* gA1 = h + (size_t)slot1 * FFN + scol;
    const ushort* gB0 = W2 + ((size_t)e * HIDDEN + tile_n * 128 + srow) * FFN + scol;

    f4v acc[8][2];
#pragma unroll
    for (int i = 0; i < 8; ++i)
#pragma unroll
        for (int j = 0; j < 2; ++j) { f4v z = {0.f, 0.f, 0.f, 0.f}; acc[i][j] = z; }

    const int wm  = wv >> 2;          // 0..1
    const int wn  = wv & 3;           // 0..3 (N: 32 cols each)
    const int l15 = lane & 15;
    const int lq  = lane >> 4;

    const int NT = FFN / 32;          // 128

    // prologue: stage tiles 0,1 -> bufs 0,1 (6 calls in flight)
#pragma unroll
    for (int p = 0; p < 2; ++p) {
        GLDS16(gA0 + p * 32, As + p * 8192 + wv * 512);
        GLDS16(gA1 + p * 32, As + p * 8192 + 4096 + wv * 512);
        GLDS16(gB0 + p * 32, Bs + p * 4096 + wv * 512);
    }
    asm volatile("s_waitcnt vmcnt(3)" ::: "memory");   // tile 0 landed; tile 1 in flight
    __builtin_amdgcn_s_barrier();
    __builtin_amdgcn_sched_barrier(0);

    for (int t0 = 0; t0 < NT; t0 += 3) {
        G2_TILE(t0 + 0, As + 0 * 8192, Bs + 0 * 4096, As + 2 * 8192, Bs + 2 * 4096);
        G2_TILE(t0 + 1, As + 1 * 8192, Bs + 1 * 4096, As + 0 * 8192, Bs + 0 * 4096);
        G2_TILE(t0 + 2, As + 2 * 8192, Bs + 2 * 4096, As + 1 * 8192, Bs + 1 * 4096);
    }

    const int mrem = n_e - tile_m * 256;
#pragma unroll
    for (int i = 0; i < 8; ++i) {
#pragma unroll
        for (int rr = 0; rr < 4; ++rr) {
            const int m_loc = wm * 128 + i * 16 + lq * 4 + rr;
            if (m_loc < mrem) {
                const int slot  = base + tile_m * 256 + m_loc;
                const float wgt = weight_list[slot];
#pragma unroll
                for (int j = 0; j < 2; ++j) {
                    const int colD = tile_n * 128 + wn * 32 + j * 16 + l15;
                    const float v = acc[i][j][rr] + b2[e * HIDDEN + colD];
                    y[(size_t)slot * HIDDEN + colD] = f2bf(v * wgt);
                }
            }
        }
    }
}

// ---------------- combine: out[t] = y[slot0] + y[slot1]  (fp32 out) ----------------
__global__ void combine_kernel(const int* __restrict__ slot_of, const ushort* __restrict__ y,
                               float* __restrict__ out) {
    const int idx = blockIdx.x * blockDim.x + threadIdx.x;  // T * D/4 threads
    const int t = idx >> 8;             // D/4 = 256 vec4 per token
    const int d = (idx & 255) * 4;
    const int s0 = slot_of[t * 2 + 0];
    const int s1 = slot_of[t * 2 + 1];
    const ushort4 a = *(const ushort4*)(y + (size_t)s0 * HIDDEN + d);
    const ushort4 b = *(const ushort4*)(y + (size_t)s1 * HIDDEN + d);
    float4 o;
    o.x = bf2f(a.x) + bf2f(b.x);
    o.y = bf2f(a.y) + bf2f(b.y);
    o.z = bf2f(a.z) + bf2f(b.z);
    o.w = bf2f(a.w) + bf2f(b.w);
    *(float4*)(out + (size_t)t * HIDDEN + d) = o;
}

extern "C" void kernel_launch(void* const* d_in, const int* in_sizes, int n_in,
                              void* d_out, int out_size, void* d_ws, size_t ws_size,
                              hipStream_t stream) {
    const float* x  = (const float*)d_in[0];   // [T, D] fp32
    const float* Wr = (const float*)d_in[1];   // [E, D]
    const float* W1 = (const float*)d_in[2];   // [E, F, D]
    const float* b1 = (const float*)d_in[3];   // [E, F]
    const float* W2 = (const float*)d_in[4];   // [E, D, F]
    const float* b2 = (const float*)d_in[5];   // [E, D]
    float* out = (float*)d_out;

    char* ws = (char*)d_ws;
    int*    counts      = (int*)(ws + 0);
    int*    offsets     = (int*)(ws + 256);
    int*    cursors     = (int*)(ws + 512);
    int*    tiles       = (int*)(ws + 768);            // NENT ints
    int*    topk_idx    = (int*)(ws + 2048);           // 32 KB
    float*  topk_w      = (float*)(ws + 2048 + 32768); // 16 KB
    int*    slot_of     = (int*)(ws + 2048 + 65536);   // 32 KB
    int*    token_list  = (int*)(ws + 2048 + 98304);   // 32 KB
    float*  weight_list = (float*)(ws + 2048 + 131072);// 32 KB
    ushort* x_bf        = (ushort*)(ws + (1 << 20));                             //  8 MB
    ushort* wbuf        = (ushort*)(ws + (1 << 20) + 8388608);                   // 64 MB (shared W1/W2)
    ushort* h           = (ushort*)(ws + (1 << 20) + 8388608 + 67108864);        // 64 MB
    ushort* y           = (ushort*)(ws + (1 << 20) + 8388608 + 2 * 67108864ull); // 16 MB

    const int NW = NEXP * FFN * HIDDEN;  // 33554432 elements per weight tensor

    hipMemsetAsync(counts, 0, 64, stream);
    // router + fused x->bf16
    router_kernel<<<TOKENS, 64, 0, stream>>>(x, Wr, counts, topk_idx, topk_w, x_bf);
    // W1 -> bf16 (into shared wbuf)
    conv_kernel<<<(NW / 4) / 256, 256, 0, stream>>>((const float4*)W1, (ushort4*)wbuf);

    prefix_kernel<<<1, 64, 0, stream>>>(counts, offsets, cursors, tiles);
    scatter_kernel<<<ASSIGN / 256, 256, 0, stream>>>(topk_idx, topk_w, cursors,
                                                     token_list, weight_list, slot_of);

    // grid: (tile_n fastest, entry) -> B-panel-sharing blocks land on one XCD
    gemm1_kernel<<<dim3(FFN / 256, NENT), 512, 0, stream>>>(
        x_bf, wbuf, b1, token_list, counts, offsets, tiles, h);

    // W2 -> bf16 (reuse wbuf; stream-serial so gemm1 has finished reading W1)
    conv_kernel<<<(NW / 4) / 256, 256, 0, stream>>>((const float4*)W2, (ushort4*)wbuf);

    gemm2_kernel<<<dim3(HIDDEN / 128, NENT), 512, 0, stream>>>(
        h, wbuf, b2, weight_list, counts, offsets, tiles, y);

    combine_kernel<<<(TOKENS * HIDDEN / 4) / 256, 256, 0, stream>>>(slot_of, y, out);
}